// Round 1
// baseline (1577.019 us; speedup 1.0000x reference)
//
#include <hip/hip_runtime.h>

#define N_NODES 30000
#define N_EDGES 150000
#define N_REL 10
#define DIM 256

typedef __attribute__((ext_vector_type(8))) short bf16x8;
typedef __attribute__((ext_vector_type(4))) float f32x4;

__device__ __forceinline__ unsigned short f2bf(float f) {
  union { float f; unsigned int u; } v; v.f = f;
  unsigned int u = v.u;
  unsigned int r = u + 0x7fffu + ((u >> 16) & 1u);  // RNE
  return (unsigned short)(r >> 16);
}

// ---- preprocessing -------------------------------------------------------

__global__ void conv_x_kernel(const float* __restrict__ x,
                              unsigned short* __restrict__ xbf) {
  int idx = blockIdx.x * blockDim.x + threadIdx.x;  // one float4 each, exact grid
  float4 v = reinterpret_cast<const float4*>(x)[idx];
  ushort4 o;
  o.x = f2bf(v.x); o.y = f2bf(v.y); o.z = f2bf(v.z); o.w = f2bf(v.w);
  reinterpret_cast<ushort4*>(xbf)[idx] = o;
}

// wt[b][o][i] = W_b[i][o] (bf16), buckets: 0..9 fwd, 10..19 rev, 20 self
__global__ void conv_w_kernel(const float* __restrict__ Wf,
                              const float* __restrict__ Wr,
                              const float* __restrict__ Ws,
                              unsigned short* __restrict__ wt) {
  int idx = blockIdx.x * blockDim.x + threadIdx.x;  // exact grid 21*65536
  int b = idx >> 16;
  int t = idx & 65535;
  int o = t >> 8, i = t & 255;
  const float* src = (b < N_REL) ? (Wf + (size_t)b * 65536)
                   : (b < 2 * N_REL) ? (Wr + (size_t)(b - N_REL) * 65536)
                   : Ws;
  wt[idx] = f2bf(src[i * 256 + o]);
}

__global__ void zero_meta_kernel(int* counts) {
  if (threadIdx.x < N_REL) counts[threadIdx.x] = 0;
}

__global__ void hist_kernel(const int* __restrict__ rel, int* __restrict__ counts) {
  int e = blockIdx.x * blockDim.x + threadIdx.x;
  if (e < N_EDGES) atomicAdd(&counts[rel[e]], 1);
}

__global__ void scan_kernel(const int* __restrict__ counts,
                            int* __restrict__ rel_start,
                            int* __restrict__ cursor) {
  int s = 0;
  for (int r = 0; r < N_REL; ++r) { rel_start[r] = s; cursor[r] = s; s += counts[r]; }
  rel_start[N_REL] = s;
}

__global__ void scatter_kernel(const int* __restrict__ rel,
                               int* __restrict__ cursor,
                               int* __restrict__ perm) {
  int e = blockIdx.x * blockDim.x + threadIdx.x;
  if (e < N_EDGES) {
    int pos = atomicAdd(&cursor[rel[e]], 1);
    perm[pos] = e;
  }
}

// ---- self GEMM: out = x @ W_self + b_self (plain stores, runs first) -----

__global__ void self_gemm_kernel(const unsigned short* __restrict__ xbf,
                                 const unsigned short* __restrict__ wt_self,
                                 const float* __restrict__ b_self,
                                 float* __restrict__ out) {
  const int tid = threadIdx.x;
  const int wave = tid >> 6, lane = tid & 63;
  const int lm = lane & 15, q = lane >> 4;
  const int nb = wave * 64;
  const int row0 = blockIdx.x * 64;

  const unsigned short* xr[4];
  #pragma unroll
  for (int mi = 0; mi < 4; ++mi) {
    int r = row0 + mi * 16 + lm;
    int rc = r < N_NODES ? r : N_NODES - 1;
    xr[mi] = xbf + (size_t)rc * DIM + q * 8;
  }
  const unsigned short* wr[4];
  #pragma unroll
  for (int ni = 0; ni < 4; ++ni)
    wr[ni] = wt_self + (size_t)(nb + ni * 16 + lm) * DIM + q * 8;

  f32x4 acc[4][4];
  #pragma unroll
  for (int mi = 0; mi < 4; ++mi)
    #pragma unroll
    for (int ni = 0; ni < 4; ++ni)
      acc[mi][ni] = (f32x4){0.f, 0.f, 0.f, 0.f};

  #pragma unroll
  for (int k0 = 0; k0 < DIM; k0 += 32) {
    bf16x8 a[4], b[4];
    #pragma unroll
    for (int mi = 0; mi < 4; ++mi) a[mi] = *reinterpret_cast<const bf16x8*>(xr[mi] + k0);
    #pragma unroll
    for (int ni = 0; ni < 4; ++ni) b[ni] = *reinterpret_cast<const bf16x8*>(wr[ni] + k0);
    #pragma unroll
    for (int mi = 0; mi < 4; ++mi)
      #pragma unroll
      for (int ni = 0; ni < 4; ++ni)
        acc[mi][ni] = __builtin_amdgcn_mfma_f32_16x16x32_bf16(a[mi], b[ni], acc[mi][ni], 0, 0, 0);
  }

  float bias[4];
  #pragma unroll
  for (int ni = 0; ni < 4; ++ni) bias[ni] = b_self[nb + ni * 16 + lm];

  #pragma unroll
  for (int mi = 0; mi < 4; ++mi) {
    #pragma unroll
    for (int reg = 0; reg < 4; ++reg) {
      int row = row0 + mi * 16 + q * 4 + reg;  // C/D: row = quad*4 + reg
      if (row < N_NODES) {
        #pragma unroll
        for (int ni = 0; ni < 4; ++ni)
          out[(size_t)row * DIM + nb + ni * 16 + lm] = acc[mi][ni][reg] + bias[ni];
      }
    }
  }
}

// ---- edge GEMM: per (rel,dir) bucket, gather -> GEMM -> atomic scatter ---

__global__ void edge_gemm_kernel(const unsigned short* __restrict__ xbf,
                                 const unsigned short* __restrict__ wt,
                                 const float* __restrict__ b_fwd,
                                 const float* __restrict__ b_rev,
                                 const int* __restrict__ perm,
                                 const int* __restrict__ rel_start,
                                 const int* __restrict__ dep,
                                 const int* __restrict__ gov,
                                 float* __restrict__ out) {
  const int bucket = blockIdx.y;
  const int r = bucket % N_REL;
  const bool fwd = bucket < N_REL;
  const int beg = rel_start[r];
  const int cnt = rel_start[r + 1] - beg;
  const int ntiles = (cnt + 63) >> 6;

  const int tid = threadIdx.x;
  const int wave = tid >> 6, lane = tid & 63;
  const int lm = lane & 15, q = lane >> 4;
  const int nb = wave * 64;

  __shared__ int s_src[64], s_dst[64];

  const unsigned short* wr[4];
  #pragma unroll
  for (int ni = 0; ni < 4; ++ni)
    wr[ni] = wt + (size_t)bucket * DIM * DIM + (size_t)(nb + ni * 16 + lm) * DIM + q * 8;

  const float* bptr = (fwd ? b_fwd : b_rev) + r * DIM;
  float bias[4];
  #pragma unroll
  for (int ni = 0; ni < 4; ++ni) bias[ni] = bptr[nb + ni * 16 + lm];

  for (int t = blockIdx.x; t < ntiles; t += gridDim.x) {
    const int tile0 = t << 6;
    const int rows_valid = min(64, cnt - tile0);

    if (tid < 64) {
      int s = 0, d = -1;
      if (tid < rows_valid) {
        int e = perm[beg + tile0 + tid];
        int gv = gov[e], dp = dep[e];
        s = fwd ? gv : dp;
        d = fwd ? dp : gv;
      }
      s_src[tid] = s;
      s_dst[tid] = d;
    }
    __syncthreads();

    const unsigned short* xr[4];
    #pragma unroll
    for (int mi = 0; mi < 4; ++mi)
      xr[mi] = xbf + (size_t)s_src[mi * 16 + lm] * DIM + q * 8;

    f32x4 acc[4][4];
    #pragma unroll
    for (int mi = 0; mi < 4; ++mi)
      #pragma unroll
      for (int ni = 0; ni < 4; ++ni)
        acc[mi][ni] = (f32x4){0.f, 0.f, 0.f, 0.f};

    #pragma unroll
    for (int k0 = 0; k0 < DIM; k0 += 32) {
      bf16x8 a[4], b[4];
      #pragma unroll
      for (int mi = 0; mi < 4; ++mi) a[mi] = *reinterpret_cast<const bf16x8*>(xr[mi] + k0);
      #pragma unroll
      for (int ni = 0; ni < 4; ++ni) b[ni] = *reinterpret_cast<const bf16x8*>(wr[ni] + k0);
      #pragma unroll
      for (int mi = 0; mi < 4; ++mi)
        #pragma unroll
        for (int ni = 0; ni < 4; ++ni)
          acc[mi][ni] = __builtin_amdgcn_mfma_f32_16x16x32_bf16(a[mi], b[ni], acc[mi][ni], 0, 0, 0);
    }

    #pragma unroll
    for (int mi = 0; mi < 4; ++mi) {
      #pragma unroll
      for (int reg = 0; reg < 4; ++reg) {
        int row = mi * 16 + q * 4 + reg;
        if (row < rows_valid) {
          int dst = s_dst[row];
          float* op = out + (size_t)dst * DIM + nb + lm;
          #pragma unroll
          for (int ni = 0; ni < 4; ++ni)
            atomicAdd(op + ni * 16, acc[mi][ni][reg] + bias[ni]);
        }
      }
    }
    __syncthreads();
  }
}

// ---- launch --------------------------------------------------------------

extern "C" void kernel_launch(void* const* d_in, const int* in_sizes, int n_in,
                              void* d_out, int out_size, void* d_ws, size_t ws_size,
                              hipStream_t stream) {
  const float* x      = (const float*)d_in[0];
  const float* W_self = (const float*)d_in[1];
  const float* b_self = (const float*)d_in[2];
  const float* W_fwd  = (const float*)d_in[3];
  const float* b_fwd  = (const float*)d_in[4];
  const float* W_rev  = (const float*)d_in[5];
  const float* b_rev  = (const float*)d_in[6];
  const int* dep = (const int*)d_in[7];
  const int* rel = (const int*)d_in[8];
  const int* gov = (const int*)d_in[9];
  float* out = (float*)d_out;

  char* ws = (char*)d_ws;
  unsigned short* xbf = (unsigned short*)ws;  ws += (size_t)N_NODES * DIM * 2;   // 15.36 MB
  unsigned short* wt  = (unsigned short*)ws;  ws += (size_t)21 * DIM * DIM * 2;  // 2.75 MB
  int* perm      = (int*)ws;                  ws += (size_t)N_EDGES * 4;         // 0.6 MB
  int* counts    = (int*)ws;                  ws += 16 * 4;
  int* rel_start = (int*)ws;                  ws += 16 * 4;
  int* cursor    = (int*)ws;

  conv_x_kernel<<<N_NODES * DIM / 4 / 256, 256, 0, stream>>>(x, xbf);
  conv_w_kernel<<<21 * DIM * DIM / 256, 256, 0, stream>>>(W_fwd, W_rev, W_self, wt);
  zero_meta_kernel<<<1, 64, 0, stream>>>(counts);
  hist_kernel<<<(N_EDGES + 255) / 256, 256, 0, stream>>>(rel, counts);
  scan_kernel<<<1, 1, 0, stream>>>(counts, rel_start, cursor);
  scatter_kernel<<<(N_EDGES + 255) / 256, 256, 0, stream>>>(rel, cursor, perm);
  // self GEMM first: plain stores initialize every out element (stream-ordered
  // before the edge kernel's atomics -> no race, no memset needed)
  self_gemm_kernel<<<(N_NODES + 63) / 64, 256, 0, stream>>>(
      xbf, wt + (size_t)20 * DIM * DIM, b_self, out);
  edge_gemm_kernel<<<dim3(260, 20), 256, 0, stream>>>(
      xbf, wt, b_fwd, b_rev, perm, rel_start, dep, gov, out);
}

// Round 2
// 520.363 us; speedup vs baseline: 3.0306x; 3.0306x over previous
//
#include <hip/hip_runtime.h>

#define N_NODES 30000
#define N_EDGES 150000
#define N_REL 10
#define DIM 256

#define SORT_BLOCKS 120
#define SORT_CHUNK ((N_EDGES + SORT_BLOCKS - 1) / SORT_BLOCKS)  // 1250

typedef __attribute__((ext_vector_type(8))) short bf16x8;
typedef __attribute__((ext_vector_type(4))) float f32x4;

__device__ __forceinline__ unsigned short f2bf(float f) {
  union { float f; unsigned int u; } v; v.f = f;
  unsigned int u = v.u;
  unsigned int r = u + 0x7fffu + ((u >> 16) & 1u);  // RNE
  return (unsigned short)(r >> 16);
}

// ---- preprocessing -------------------------------------------------------

__global__ void conv_x_kernel(const float* __restrict__ x,
                              unsigned short* __restrict__ xbf) {
  int idx = blockIdx.x * blockDim.x + threadIdx.x;  // one float4 each, exact grid
  float4 v = reinterpret_cast<const float4*>(x)[idx];
  ushort4 o;
  o.x = f2bf(v.x); o.y = f2bf(v.y); o.z = f2bf(v.z); o.w = f2bf(v.w);
  reinterpret_cast<ushort4*>(xbf)[idx] = o;
}

// wt[b][o][i] = W_b[i][o] (bf16), buckets: 0..9 fwd, 10..19 rev, 20 self
__global__ void conv_w_kernel(const float* __restrict__ Wf,
                              const float* __restrict__ Wr,
                              const float* __restrict__ Ws,
                              unsigned short* __restrict__ wt) {
  int idx = blockIdx.x * blockDim.x + threadIdx.x;  // exact grid 21*65536
  int b = idx >> 16;
  int t = idx & 65535;
  int o = t >> 8, i = t & 255;
  const float* src = (b < N_REL) ? (Wf + (size_t)b * 65536)
                   : (b < 2 * N_REL) ? (Wr + (size_t)(b - N_REL) * 65536)
                   : Ws;
  wt[idx] = f2bf(src[i * 256 + o]);
}

// ---- counting sort by relation (no global atomics) -----------------------

__global__ void blockhist_kernel(const int* __restrict__ rel,
                                 int* __restrict__ block_counts) {
  __shared__ int h[N_REL];
  if (threadIdx.x < N_REL) h[threadIdx.x] = 0;
  __syncthreads();
  int beg = blockIdx.x * SORT_CHUNK;
  int end = min(beg + SORT_CHUNK, N_EDGES);
  for (int e = beg + threadIdx.x; e < end; e += blockDim.x)
    atomicAdd(&h[rel[e]], 1);
  __syncthreads();
  if (threadIdx.x < N_REL)
    block_counts[blockIdx.x * N_REL + threadIdx.x] = h[threadIdx.x];
}

// single small block: totals per rel, rel_start prefix, per-block cursors
__global__ void scan_kernel(const int* __restrict__ block_counts,
                            int* __restrict__ rel_start,
                            int* __restrict__ block_offset) {
  __shared__ int tot[N_REL];
  int r = threadIdx.x;
  if (r < N_REL) {
    int s = 0;
    for (int b = 0; b < SORT_BLOCKS; ++b) s += block_counts[b * N_REL + r];
    tot[r] = s;
  }
  __syncthreads();
  if (threadIdx.x == 0) {
    int s = 0;
    for (int i = 0; i < N_REL; ++i) { rel_start[i] = s; s += tot[i]; }
    rel_start[N_REL] = s;
  }
  __syncthreads();
  if (r < N_REL) {
    int run = rel_start[r];
    for (int b = 0; b < SORT_BLOCKS; ++b) {
      block_offset[b * N_REL + r] = run;
      run += block_counts[b * N_REL + r];
    }
  }
}

__global__ void scatter2_kernel(const int* __restrict__ rel,
                                const int* __restrict__ block_offset,
                                int* __restrict__ perm) {
  __shared__ int cur[N_REL];
  if (threadIdx.x < N_REL)
    cur[threadIdx.x] = block_offset[blockIdx.x * N_REL + threadIdx.x];
  __syncthreads();
  int beg = blockIdx.x * SORT_CHUNK;
  int end = min(beg + SORT_CHUNK, N_EDGES);
  for (int e = beg + threadIdx.x; e < end; e += blockDim.x) {
    int pos = atomicAdd(&cur[rel[e]], 1);  // LDS atomic, cheap
    perm[pos] = e;
  }
}

// ---- self GEMM: out = x @ W_self + b_self (plain stores, runs first) -----

__global__ void self_gemm_kernel(const unsigned short* __restrict__ xbf,
                                 const unsigned short* __restrict__ wt_self,
                                 const float* __restrict__ b_self,
                                 float* __restrict__ out) {
  const int tid = threadIdx.x;
  const int wave = tid >> 6, lane = tid & 63;
  const int lm = lane & 15, q = lane >> 4;
  const int nb = wave * 64;
  const int row0 = blockIdx.x * 64;

  const unsigned short* xr[4];
  #pragma unroll
  for (int mi = 0; mi < 4; ++mi) {
    int r = row0 + mi * 16 + lm;
    int rc = r < N_NODES ? r : N_NODES - 1;
    xr[mi] = xbf + (size_t)rc * DIM + q * 8;
  }
  const unsigned short* wr[4];
  #pragma unroll
  for (int ni = 0; ni < 4; ++ni)
    wr[ni] = wt_self + (size_t)(nb + ni * 16 + lm) * DIM + q * 8;

  f32x4 acc[4][4];
  #pragma unroll
  for (int mi = 0; mi < 4; ++mi)
    #pragma unroll
    for (int ni = 0; ni < 4; ++ni)
      acc[mi][ni] = (f32x4){0.f, 0.f, 0.f, 0.f};

  #pragma unroll
  for (int k0 = 0; k0 < DIM; k0 += 32) {
    bf16x8 a[4], b[4];
    #pragma unroll
    for (int mi = 0; mi < 4; ++mi) a[mi] = *reinterpret_cast<const bf16x8*>(xr[mi] + k0);
    #pragma unroll
    for (int ni = 0; ni < 4; ++ni) b[ni] = *reinterpret_cast<const bf16x8*>(wr[ni] + k0);
    #pragma unroll
    for (int mi = 0; mi < 4; ++mi)
      #pragma unroll
      for (int ni = 0; ni < 4; ++ni)
        acc[mi][ni] = __builtin_amdgcn_mfma_f32_16x16x32_bf16(a[mi], b[ni], acc[mi][ni], 0, 0, 0);
  }

  float bias[4];
  #pragma unroll
  for (int ni = 0; ni < 4; ++ni) bias[ni] = b_self[nb + ni * 16 + lm];

  #pragma unroll
  for (int mi = 0; mi < 4; ++mi) {
    #pragma unroll
    for (int reg = 0; reg < 4; ++reg) {
      int row = row0 + mi * 16 + q * 4 + reg;  // C/D: row = quad*4 + reg
      if (row < N_NODES) {
        #pragma unroll
        for (int ni = 0; ni < 4; ++ni)
          out[(size_t)row * DIM + nb + ni * 16 + lm] = acc[mi][ni][reg] + bias[ni];
      }
    }
  }
}

// ---- edge GEMM: per (rel,dir) bucket, gather -> GEMM -> atomic scatter ---

__global__ void edge_gemm_kernel(const unsigned short* __restrict__ xbf,
                                 const unsigned short* __restrict__ wt,
                                 const float* __restrict__ b_fwd,
                                 const float* __restrict__ b_rev,
                                 const int* __restrict__ perm,
                                 const int* __restrict__ rel_start,
                                 const int* __restrict__ dep,
                                 const int* __restrict__ gov,
                                 float* __restrict__ out) {
  const int bucket = blockIdx.y;
  const int r = bucket % N_REL;
  const bool fwd = bucket < N_REL;
  const int beg = rel_start[r];
  const int cnt = rel_start[r + 1] - beg;
  const int ntiles = (cnt + 63) >> 6;

  const int tid = threadIdx.x;
  const int wave = tid >> 6, lane = tid & 63;
  const int lm = lane & 15, q = lane >> 4;
  const int nb = wave * 64;

  __shared__ int s_src[64], s_dst[64];

  const unsigned short* wr[4];
  #pragma unroll
  for (int ni = 0; ni < 4; ++ni)
    wr[ni] = wt + (size_t)bucket * DIM * DIM + (size_t)(nb + ni * 16 + lm) * DIM + q * 8;

  const float* bptr = (fwd ? b_fwd : b_rev) + r * DIM;
  float bias[4];
  #pragma unroll
  for (int ni = 0; ni < 4; ++ni) bias[ni] = bptr[nb + ni * 16 + lm];

  for (int t = blockIdx.x; t < ntiles; t += gridDim.x) {
    const int tile0 = t << 6;
    const int rows_valid = min(64, cnt - tile0);

    if (tid < 64) {
      int s = 0, d = -1;
      if (tid < rows_valid) {
        int e = perm[beg + tile0 + tid];
        int gv = gov[e], dp = dep[e];
        s = fwd ? gv : dp;
        d = fwd ? dp : gv;
      }
      s_src[tid] = s;
      s_dst[tid] = d;
    }
    __syncthreads();

    const unsigned short* xr[4];
    #pragma unroll
    for (int mi = 0; mi < 4; ++mi)
      xr[mi] = xbf + (size_t)s_src[mi * 16 + lm] * DIM + q * 8;

    f32x4 acc[4][4];
    #pragma unroll
    for (int mi = 0; mi < 4; ++mi)
      #pragma unroll
      for (int ni = 0; ni < 4; ++ni)
        acc[mi][ni] = (f32x4){0.f, 0.f, 0.f, 0.f};

    #pragma unroll
    for (int k0 = 0; k0 < DIM; k0 += 32) {
      bf16x8 a[4], b[4];
      #pragma unroll
      for (int mi = 0; mi < 4; ++mi) a[mi] = *reinterpret_cast<const bf16x8*>(xr[mi] + k0);
      #pragma unroll
      for (int ni = 0; ni < 4; ++ni) b[ni] = *reinterpret_cast<const bf16x8*>(wr[ni] + k0);
      #pragma unroll
      for (int mi = 0; mi < 4; ++mi)
        #pragma unroll
        for (int ni = 0; ni < 4; ++ni)
          acc[mi][ni] = __builtin_amdgcn_mfma_f32_16x16x32_bf16(a[mi], b[ni], acc[mi][ni], 0, 0, 0);
    }

    #pragma unroll
    for (int mi = 0; mi < 4; ++mi) {
      #pragma unroll
      for (int reg = 0; reg < 4; ++reg) {
        int row = mi * 16 + q * 4 + reg;
        if (row < rows_valid) {
          int dst = s_dst[row];
          float* op = out + (size_t)dst * DIM + nb + lm;
          #pragma unroll
          for (int ni = 0; ni < 4; ++ni)
            atomicAdd(op + ni * 16, acc[mi][ni][reg] + bias[ni]);
        }
      }
    }
    __syncthreads();
  }
}

// ---- launch --------------------------------------------------------------

extern "C" void kernel_launch(void* const* d_in, const int* in_sizes, int n_in,
                              void* d_out, int out_size, void* d_ws, size_t ws_size,
                              hipStream_t stream) {
  const float* x      = (const float*)d_in[0];
  const float* W_self = (const float*)d_in[1];
  const float* b_self = (const float*)d_in[2];
  const float* W_fwd  = (const float*)d_in[3];
  const float* b_fwd  = (const float*)d_in[4];
  const float* W_rev  = (const float*)d_in[5];
  const float* b_rev  = (const float*)d_in[6];
  const int* dep = (const int*)d_in[7];
  const int* rel = (const int*)d_in[8];
  const int* gov = (const int*)d_in[9];
  float* out = (float*)d_out;

  char* ws = (char*)d_ws;
  unsigned short* xbf = (unsigned short*)ws;  ws += (size_t)N_NODES * DIM * 2;   // 15.36 MB
  unsigned short* wt  = (unsigned short*)ws;  ws += (size_t)21 * DIM * DIM * 2;  // 2.75 MB
  int* perm         = (int*)ws;               ws += (size_t)N_EDGES * 4;         // 0.6 MB
  int* rel_start    = (int*)ws;               ws += 16 * 4;
  int* block_counts = (int*)ws;               ws += SORT_BLOCKS * N_REL * 4;
  int* block_offset = (int*)ws;

  conv_x_kernel<<<N_NODES * DIM / 4 / 256, 256, 0, stream>>>(x, xbf);
  conv_w_kernel<<<21 * DIM * DIM / 256, 256, 0, stream>>>(W_fwd, W_rev, W_self, wt);
  blockhist_kernel<<<SORT_BLOCKS, 256, 0, stream>>>(rel, block_counts);
  scan_kernel<<<1, 64, 0, stream>>>(block_counts, rel_start, block_offset);
  scatter2_kernel<<<SORT_BLOCKS, 256, 0, stream>>>(rel, block_offset, perm);
  // self GEMM first: plain stores initialize every out element (stream-ordered
  // before the edge kernel's atomics -> no race, no memset needed)
  self_gemm_kernel<<<(N_NODES + 63) / 64, 256, 0, stream>>>(
      xbf, wt + (size_t)20 * DIM * DIM, b_self, out);
  edge_gemm_kernel<<<dim3(260, 20), 256, 0, stream>>>(
      xbf, wt, b_fwd, b_rev, perm, rel_start, dep, gov, out);
}